// Round 7
// baseline (382.772 us; speedup 1.0000x reference)
//
#include <hip/hip_runtime.h>

// Problem constants (fixed instance): all float tensors are float32 on device.
#define NPL   16384        // nodes per level
#define DIM   64
#define CPN   8            // children per node
#define EPL   (NPL * CPN)  // edges per level block = 131072
#define NLEV  8

#define TPB   512          // 8 waves/block; 512-thread blocks compile to 92
                           // VGPRs (R0 proven). TPB=1024 pins a 64-VGPR cap
                           // -> spills (R3/R4/R5 lesson). Occupancy is scaled
                           // via GRID SIZE (blocks/CU), not block size.
#define WPB   (TPB / 64)   // 8 waves per block

// Geometry as a function of grid size NBLK:
//   NPB = NPL/NBLK nodes per block per level, NPW = NPB/WPB nodes per wave.
// NBLK=256: 1 block/CU (R0-proven, 121us). NBLK=512: 2 blocks/CU (the TLP
// experiment). Guarded by a host occupancy query so it can never hang.

// ---- write-through store (L2-bypassing, proven R6/R7): keeps L2 free of
// pre-final out data, so normal cached GATHER loads are safe (out lines enter
// L1/L2 only via our own post-final gathers). No cache-maintenance ops.
__device__ __forceinline__ void co_st(float* p, float v) {
    __hip_atomic_store(p, v, __ATOMIC_RELAXED, __HIP_MEMORY_SCOPE_AGENT);
}

__device__ __forceinline__ void load_wrow(float* dst, const float* W, int row) {
    const float4* p = (const float4*)(W + row * DIM);
    #pragma unroll
    for (int q = 0; q < DIM / 4; ++q) {
        float4 v = p[q];
        dst[4*q+0] = v.x; dst[4*q+1] = v.y;
        dst[4*q+2] = v.z; dst[4*q+3] = v.w;
    }
}

// tanh via hardware exp + rcp. |err| ~1e-6, threshold is 5.9e-2.
__device__ __forceinline__ float fast_tanh(float z) {
    z = fminf(15.f, fmaxf(-15.f, z));
    float e = __expf(-2.f * z);
    return (1.f - e) * __builtin_amdgcn_rcpf(1.f + e);
}

// Monotonic grid barrier (R6, proven): no fences, no cache walks.
// __syncthreads() drains vmcnt first, so all write-through stores of this
// block are at the coherent point before the arrive.
__device__ __forceinline__ void gridbar(int* cnt, int target) {
    __syncthreads();
    if (threadIdx.x == 0) {
        __hip_atomic_fetch_add(cnt, 1, __ATOMIC_RELAXED,
                               __HIP_MEMORY_SCOPE_AGENT);
        while (__hip_atomic_load(cnt, __ATOMIC_RELAXED,
                                 __HIP_MEMORY_SCOPE_AGENT) < target)
            __builtin_amdgcn_s_sleep(2);
    }
    asm volatile("" ::: "memory");
    __syncthreads();
}

// ------------- Phase A: x @ Wr^T for ALL 131072 rows -----------------------
// Level-0 rows go straight to out (final values; gathered cross-block later
// -> write-through). Levels 1-7 go to XR in d_ws: produced and consumed by
// the SAME wave -> normal cached path (same-XCD L2, coherent).
// (R1/R2 lesson: XR belongs in GLOBAL. VGPR-resident spilled to scratch
// (1.8 GB traffic); LDS-resident perturbed regalloc and went latency-bound.)
template<int NBLK, bool COH>
__device__ __forceinline__ void phaseA(
    const float* __restrict__ x, const float* __restrict__ Wr,
    float* __restrict__ out, float* __restrict__ XR,
    int lane, int w, int blk, float* sX4)
{
    constexpr int NPB = NPL / NBLK;
    constexpr int NPW = NPB / WPB;
    constexpr int GPL = NPW / 4;           // 4-row groups per level
    constexpr int NG  = NLEV * GPL;        // groups total per wave

    float wr[DIM];
    load_wrow(wr, Wr, lane);

    const int base = blk * NPB + w * NPW;
    const int sub  = lane >> 4;            // row within 4-row group
    const int col4 = (lane & 15) * 4;      // dim offset of this lane's float4

    float4 q0, q1, q2;
    #define ROWB(g) ((long)((g) / GPL) * NPL + base + ((g) % GPL) * 4)
    q0 = *(const float4*)&x[(ROWB(0) + sub) * DIM + col4];
    q1 = *(const float4*)&x[(ROWB(1) + sub) * DIM + col4];

    #pragma unroll
    for (int g = 0; g < NG; ++g) {
        if (g + 2 < NG)
            q2 = *(const float4*)&x[(ROWB(g + 2) + sub) * DIM + col4];

        *(float4*)&sX4[sub * DIM + col4] = q0;  // stage 4 rows (in-order DS)

        const long rb = ROWB(g);
        const int  L  = g / GPL;
        #pragma unroll
        for (int rr = 0; rr < 4; ++rr) {
            float a0 = 0.f, a1 = 0.f, a2 = 0.f, a3 = 0.f;
            const float4* A = (const float4*)&sX4[rr * DIM];   // broadcast
            #pragma unroll
            for (int k = 0; k < DIM / 4; ++k) {
                float4 av = A[k];
                a0 += av.x * wr[4*k+0];
                a1 += av.y * wr[4*k+1];
                a2 += av.z * wr[4*k+2];
                a3 += av.w * wr[4*k+3];
            }
            float r = (a0 + a1) + (a2 + a3);
            const long gg = rb + rr;
            if (L == 0) {
                float* d = &out[gg * DIM + lane];
                if (COH) co_st(d, r); else *d = r;
            } else {
                XR[gg * DIM + lane] = r;          // same-wave consumer: cached
            }
        }
        q0 = q1; q1 = q2;
    }
    #undef ROWB
}

// -------- Phase B: out[g] = tanh(XR[g] + agg·Wl^T + b) for one level -------
// vidx: lane l holds child index of node (pbase + l/8), slot (l%8), preloaded
// at kernel start (lanes 0..NPW*8-1 used). Gathers are NORMAL CACHED loads.
// Stores are write-through. 4-SLOT ring, prefetch distance 3: issue slot
// (c+3)&3 can never collide with consume slot c&3.
template<int NBLK, bool COH>
__device__ __forceinline__ void phaseB(
    int vidx, const float* __restrict__ XR, float* __restrict__ out,
    const float* wl, float bias, int L, int lane, int w, int blk, float* sA)
{
    constexpr int NPB = NPL / NBLK;
    constexpr int NPW = NPB / WPB;

    const int  pbase = blk * NPB + w * NPW;
    const long gbase = (long)L * NPL;

    float g[4][CPN];
    float xr[4];

    #define ISSUE(c, s)                                                       \
        {                                                                     \
            _Pragma("unroll")                                                 \
            for (int j = 0; j < CPN; ++j) {                                   \
                int si = __builtin_amdgcn_readlane(vidx, (c) * CPN + j);      \
                g[s][j] = out[(long)si * DIM + lane];   /* cached gather */   \
            }                                                                 \
            xr[s] = XR[(gbase + pbase + (c)) * DIM + lane];                   \
        }

    ISSUE(0, 0);
    ISSUE(1, 1);
    ISSUE(2, 2);

    #pragma unroll
    for (int c = 0; c < NPW; ++c) {
        const int slot = c & 3;
        if (c + 3 < NPW) ISSUE(c + 3, (c + 3) & 3);   // != slot, always

        // Tree-sum the 8 children (3-deep instead of 8-deep chain).
        float s0 = g[slot][0] + g[slot][1];
        float s1 = g[slot][2] + g[slot][3];
        float s2 = g[slot][4] + g[slot][5];
        float s3 = g[slot][6] + g[slot][7];
        float agg = (s0 + s1) + (s2 + s3);
        sA[lane] = agg;                            // per-wave slot, in-order DS

        float a0 = 0.f, a1 = 0.f, a2 = 0.f, a3 = bias + xr[slot];
        const float4* B = (const float4*)sA;       // broadcast: conflict-free
        #pragma unroll
        for (int k = 0; k < DIM / 4; ++k) {
            float4 bv = B[k];
            a0 += bv.x * wl[4*k+0];
            a1 += bv.y * wl[4*k+1];
            a2 += bv.z * wl[4*k+2];
            a3 += bv.w * wl[4*k+3];
        }
        float r = fast_tanh((a0 + a1) + (a2 + a3));
        float* d = &out[(gbase + pbase + c) * DIM + lane];
        if (COH) co_st(d, r); else *d = r;
    }
    #undef ISSUE
}

// ---------------- Fused cooperative kernel (1 dispatch) ----------------
// Template on grid size: dag_fused<256> is the proven R0 config (1 block/CU);
// dag_fused<512> is the 2-blocks/CU TLP experiment. Host picks via occupancy
// query, so a non-co-residable grid is never launched (no hang possible).
template<int NBLK>
__global__ __launch_bounds__(TPB, 2) void dag_fused(
    const float* __restrict__ x, const int* __restrict__ src,
    const float* __restrict__ Wl, const float* __restrict__ bl,
    const float* __restrict__ Wr, float* __restrict__ out,
    float* __restrict__ ws)
{
    constexpr int NPB = NPL / NBLK;
    constexpr int NPW = NPB / WPB;

    __shared__ __align__(16) float sbuf[WPB][256];

    const int lane = threadIdx.x & 63;
    const int w    = threadIdx.x >> 6;

    int*   barcnt = (int*)ws;
    float* XR     = ws + 64;     // 256 B offset; 33.5 MB region in d_ws

    // Preload ALL levels' child indices (one coalesced load each): idx-load
    // latency never touches the per-level critical path. Lanes 0..NPW*8-1
    // are meaningful (readlane stays below that); others load dead data.
    const int pbase = blockIdx.x * NPB + w * NPW;
    int vidx[NLEV - 1];
    #pragma unroll
    for (int L = 1; L < NLEV; ++L)
        vidx[L - 1] = src[(long)(L - 1) * EPL + pbase * CPN + lane];

    phaseA<NBLK, true>(x, Wr, out, XR, lane, w, blockIdx.x, sbuf[w]);
    gridbar(barcnt, NBLK);

    float wl[DIM];
    load_wrow(wl, Wl, lane);
    const float bias = bl[lane];

    #pragma unroll
    for (int L = 1; L < NLEV; ++L) {
        phaseB<NBLK, true>(vidx[L - 1], XR, out, wl, bias, L, lane, w,
                           blockIdx.x, sbuf[w]);
        if (L + 1 < NLEV)
            gridbar(barcnt, (L + 1) * NBLK);
    }
}

// ---------------- Fallback: normal launches (kernel-boundary coherence) ----
__global__ __launch_bounds__(TPB) void dag_phaseA_k(
    const float* __restrict__ x, const float* __restrict__ Wr,
    float* __restrict__ out, float* __restrict__ ws)
{
    __shared__ __align__(16) float sbuf[WPB][256];
    const int lane = threadIdx.x & 63;
    const int w    = threadIdx.x >> 6;
    phaseA<256, false>(x, Wr, out, ws + 64, lane, w, blockIdx.x, sbuf[w]);
}

__global__ __launch_bounds__(TPB) void dag_phaseB_k(
    const int* __restrict__ src, const float* __restrict__ Wl,
    const float* __restrict__ bl, float* __restrict__ out,
    float* __restrict__ ws, int L)
{
    __shared__ __align__(16) float sbuf[WPB][256];
    const int lane = threadIdx.x & 63;
    const int w    = threadIdx.x >> 6;
    constexpr int NPB = NPL / 256;
    constexpr int NPW = NPB / WPB;
    const int pbase = blockIdx.x * NPB + w * NPW;
    int vidx = src[(long)(L - 1) * EPL + pbase * CPN + lane];
    float wl[DIM];
    load_wrow(wl, Wl, lane);
    phaseB<256, false>(vidx, ws + 64, out, wl, bl[lane], L, lane, w,
                       blockIdx.x, sbuf[w]);
}

extern "C" void kernel_launch(void* const* d_in, const int* in_sizes, int n_in,
                              void* d_out, int out_size, void* d_ws, size_t ws_size,
                              hipStream_t stream) {
    const float* x  = (const float*)d_in[0];   // [131072,64] f32
    const int*   ei = (const int*)d_in[1];     // [2, 917504] int32
    const float* Wl = (const float*)d_in[2];   // [64,64] f32
    const float* bl = (const float*)d_in[3];   // [64]    f32
    const float* Wr = (const float*)d_in[4];   // [64,64] f32
    float* out = (float*)d_out;                // [131072,64] f32
    float* ws  = (float*)d_ws;                 // [0..63]=barrier, [64..]=XR

    const int* src = ei;                       // first E entries = src row

    // Zero the barrier counter inside the captured work (d_ws is re-poisoned
    // 0xAA before every timed launch). XR needs no init (fully overwritten).
    hipMemsetAsync(ws, 0, 256, stream);

    void* args[] = {(void*)&x, (void*)&src, (void*)&Wl, (void*)&bl,
                    (void*)&Wr, (void*)&out, (void*)&ws};

    // R6 lesson: never launch a cooperative grid the runtime might not
    // co-schedule. Query first; only attempt 512 blocks if >=2 blocks/CU.
    hipError_t e = hipErrorUnknown;
    int maxBlk = 0;
    if (hipOccupancyMaxActiveBlocksPerMultiprocessor(
            &maxBlk, (const void*)dag_fused<512>, TPB, 0) == hipSuccess &&
        maxBlk >= 2) {
        e = hipLaunchCooperativeKernel((const void*)dag_fused<512>,
                                       dim3(512), dim3(TPB), args, 0, stream);
        if (e != hipSuccess) (void)hipGetLastError();
    }
    if (e != hipSuccess) {
        e = hipLaunchCooperativeKernel((const void*)dag_fused<256>,
                                       dim3(256), dim3(TPB), args, 0, stream);
        if (e != hipSuccess) (void)hipGetLastError();
    }
    if (e != hipSuccess) {
        hipLaunchKernelGGL(dag_phaseA_k, dim3(256), dim3(TPB), 0, stream,
                           x, Wr, out, ws);
        for (int L = 1; L < NLEV; ++L) {
            hipLaunchKernelGGL(dag_phaseB_k, dim3(256), dim3(TPB), 0, stream,
                               src, Wl, bl, out, ws, L);
        }
    }
}

// Round 8
// 199.526 us; speedup vs baseline: 1.9184x; 1.9184x over previous
//
#include <hip/hip_runtime.h>

// Problem constants (fixed instance): all float tensors are float32 on device.
#define NPL   16384        // nodes per level
#define DIM   64
#define CPN   8            // children per node
#define EPL   (NPL * CPN)  // edges per level block = 131072
#define NLEV  8

#define TPB     512        // 8 waves/block -> 92 VGPRs, no spill (R0 proven).
                           // TPB=1024 pins a 64-VGPR cap -> spills (R3-R5).
#define WPB     (TPB / 64)
#define CBLOCKS 256        // 1 block/CU. 512 (2/CU) measured 2.25x WORSE (R7):
                           // barrier cost superlinear in arrivals; TLP closed.
#define NPB     (NPL / CBLOCKS)   // 64 nodes per block per level
#define NPW     (NPB / WPB)       // 8 nodes per wave per level

// Tree-barrier groups (R8): 8 groups x 32 blocks distributes the single
// hot counter line across 17 lines -> ~8x less fabric contention.
#define NGRP  8
#define GSZ   (CBLOCKS / NGRP)    // 32

// ws int-slot layout (each slot 64 ints = 256 B apart, separate lines):
//   grpCnt[g] = wsI + g*64        (g=0..7)   arrival counters, monotonic
//   glbCnt    = wsI + 8*64                   global counter, monotonic
//   grpRel[g] = wsI + (9+g)*64               release flags (= round done)
// XR region starts at ws + 2048 floats (8 KiB), zeroed slots via memset.

// ---- write-through store (L2-bypassing, proven): keeps L2 free of pre-final
// out data, so normal cached GATHER loads are safe. No cache-maintenance ops.
__device__ __forceinline__ void co_st(float* p, float v) {
    __hip_atomic_store(p, v, __ATOMIC_RELAXED, __HIP_MEMORY_SCOPE_AGENT);
}

__device__ __forceinline__ void load_wrow(float* dst, const float* W, int row) {
    const float4* p = (const float4*)(W + row * DIM);
    #pragma unroll
    for (int q = 0; q < DIM / 4; ++q) {
        float4 v = p[q];
        dst[4*q+0] = v.x; dst[4*q+1] = v.y;
        dst[4*q+2] = v.z; dst[4*q+3] = v.w;
    }
}

// tanh via hardware exp + rcp. |err| ~1e-6, threshold is 5.9e-2.
__device__ __forceinline__ float fast_tanh(float z) {
    z = fminf(15.f, fmaxf(-15.f, z));
    float e = __expf(-2.f * z);
    return (1.f - e) * __builtin_amdgcn_rcpf(1.f + e);
}

// ---- Two-level monotonic grid barrier (R8) --------------------------------
// Semantics identical to the proven flat gridbar (relaxed atomics, vmcnt
// drained by __syncthreads before arrival, compiler fence after), but the
// 256 arrivals/polls are spread over 17 cache lines instead of 1:
//   - 32 adds per group counter (8 lines in parallel)
//   - 8 adds to the global counter; only 8 blocks ever poll it
//   - 248 blocks poll their group's release flag (31 pollers/line)
// Monotonic rounds: no resets, no ABA, no deadlock path (cooperative launch
// guarantees co-residency; counts only grow).
__device__ __forceinline__ void gridbar_tree(int* wsI, int round) {
    __syncthreads();                       // drains vmcnt: stores coherent
    if (threadIdx.x == 0) {
        const int g   = blockIdx.x >> 5;   // group 0..7 (32 blocks each)
        int* gc  = wsI + g * 64;
        int* glb = wsI + 8 * 64;
        int* rel = wsI + (9 + g) * 64;
        int prev = __hip_atomic_fetch_add(gc, 1, __ATOMIC_RELAXED,
                                          __HIP_MEMORY_SCOPE_AGENT);
        if (prev == round * GSZ + (GSZ - 1)) {      // last arrival in group
            __hip_atomic_fetch_add(glb, 1, __ATOMIC_RELAXED,
                                   __HIP_MEMORY_SCOPE_AGENT);
            while (__hip_atomic_load(glb, __ATOMIC_RELAXED,
                                     __HIP_MEMORY_SCOPE_AGENT)
                   < (round + 1) * NGRP)
                __builtin_amdgcn_s_sleep(1);
            __hip_atomic_store(rel, round + 1, __ATOMIC_RELAXED,
                               __HIP_MEMORY_SCOPE_AGENT);
        } else {
            while (__hip_atomic_load(rel, __ATOMIC_RELAXED,
                                     __HIP_MEMORY_SCOPE_AGENT) < round + 1)
                __builtin_amdgcn_s_sleep(2);
        }
    }
    asm volatile("" ::: "memory");
    __syncthreads();
}

// ------------- Phase A: x @ Wr^T for ALL 131072 rows -----------------------
// Level-0 rows go straight to out (final values; gathered cross-block later
// -> write-through). Levels 1-7 go to XR in d_ws: produced and consumed by
// the SAME wave -> normal cached path. (R1/R2: XR belongs in GLOBAL; VGPR
// home spilled, LDS home perturbed regalloc. Traffic is not the bottleneck.)
template<bool COH>
__device__ __forceinline__ void phaseA(
    const float* __restrict__ x, const float* __restrict__ Wr,
    float* __restrict__ out, float* __restrict__ XR,
    int lane, int w, int blk, float* sX4)
{
    constexpr int GPL = NPW / 4;           // 4-row groups per level (2)
    constexpr int NG  = NLEV * GPL;        // 16 groups total per wave

    float wr[DIM];
    load_wrow(wr, Wr, lane);

    const int base = blk * NPB + w * NPW;
    const int sub  = lane >> 4;            // row within 4-row group
    const int col4 = (lane & 15) * 4;      // dim offset of this lane's float4

    float4 q0, q1, q2;
    #define ROWB(g) ((long)((g) / GPL) * NPL + base + ((g) % GPL) * 4)
    q0 = *(const float4*)&x[(ROWB(0) + sub) * DIM + col4];
    q1 = *(const float4*)&x[(ROWB(1) + sub) * DIM + col4];

    #pragma unroll
    for (int g = 0; g < NG; ++g) {
        if (g + 2 < NG)
            q2 = *(const float4*)&x[(ROWB(g + 2) + sub) * DIM + col4];

        *(float4*)&sX4[sub * DIM + col4] = q0;  // stage 4 rows (in-order DS)

        const long rb = ROWB(g);
        const int  L  = g / GPL;
        #pragma unroll
        for (int rr = 0; rr < 4; ++rr) {
            float a0 = 0.f, a1 = 0.f, a2 = 0.f, a3 = 0.f;
            const float4* A = (const float4*)&sX4[rr * DIM];   // broadcast
            #pragma unroll
            for (int k = 0; k < DIM / 4; ++k) {
                float4 av = A[k];
                a0 += av.x * wr[4*k+0];
                a1 += av.y * wr[4*k+1];
                a2 += av.z * wr[4*k+2];
                a3 += av.w * wr[4*k+3];
            }
            float r = (a0 + a1) + (a2 + a3);
            const long gg = rb + rr;
            if (L == 0) {
                float* d = &out[gg * DIM + lane];
                if (COH) co_st(d, r); else *d = r;
            } else {
                XR[gg * DIM + lane] = r;          // same-wave consumer: cached
            }
        }
        q0 = q1; q1 = q2;
    }
    #undef ROWB
}

// -------- Phase B: out[g] = tanh(XR[g] + agg·Wl^T + b) for one level -------
// vidx: lane l holds child index of node (pbase + l/8), slot (l%8), preloaded
// at kernel start. Gathers are NORMAL CACHED loads. Stores are write-through.
// 4-SLOT ring, prefetch distance 3: issue slot (c+3)&3 never collides with
// consume slot c&3.
template<bool COH>
__device__ __forceinline__ void phaseB(
    int vidx, const float* __restrict__ XR, float* __restrict__ out,
    const float* wl, float bias, int L, int lane, int w, int blk, float* sA)
{
    const int  pbase = blk * NPB + w * NPW;
    const long gbase = (long)L * NPL;

    float g[4][CPN];
    float xr[4];

    #define ISSUE(c, s)                                                       \
        {                                                                     \
            _Pragma("unroll")                                                 \
            for (int j = 0; j < CPN; ++j) {                                   \
                int si = __builtin_amdgcn_readlane(vidx, (c) * CPN + j);      \
                g[s][j] = out[(long)si * DIM + lane];   /* cached gather */   \
            }                                                                 \
            xr[s] = XR[(gbase + pbase + (c)) * DIM + lane];                   \
        }

    ISSUE(0, 0);
    ISSUE(1, 1);
    ISSUE(2, 2);

    #pragma unroll
    for (int c = 0; c < NPW; ++c) {
        const int slot = c & 3;
        if (c + 3 < NPW) ISSUE(c + 3, (c + 3) & 3);   // != slot, always

        // Tree-sum the 8 children (3-deep instead of 8-deep chain).
        float s0 = g[slot][0] + g[slot][1];
        float s1 = g[slot][2] + g[slot][3];
        float s2 = g[slot][4] + g[slot][5];
        float s3 = g[slot][6] + g[slot][7];
        float agg = (s0 + s1) + (s2 + s3);
        sA[lane] = agg;                            // per-wave slot, in-order DS

        float a0 = 0.f, a1 = 0.f, a2 = 0.f, a3 = bias + xr[slot];
        const float4* B = (const float4*)sA;       // broadcast: conflict-free
        #pragma unroll
        for (int k = 0; k < DIM / 4; ++k) {
            float4 bv = B[k];
            a0 += bv.x * wl[4*k+0];
            a1 += bv.y * wl[4*k+1];
            a2 += bv.z * wl[4*k+2];
            a3 += bv.w * wl[4*k+3];
        }
        float r = fast_tanh((a0 + a1) + (a2 + a3));
        float* d = &out[(gbase + pbase + c) * DIM + lane];
        if (COH) co_st(d, r); else *d = r;
    }
    #undef ISSUE
}

// ---------------- Fused cooperative kernel (1 dispatch) ----------------
__global__ __launch_bounds__(TPB, 2) void dag_fused(
    const float* __restrict__ x, const int* __restrict__ src,
    const float* __restrict__ Wl, const float* __restrict__ bl,
    const float* __restrict__ Wr, float* __restrict__ out,
    float* __restrict__ ws)
{
    __shared__ __align__(16) float sbuf[WPB][256];

    const int lane = threadIdx.x & 63;
    const int w    = threadIdx.x >> 6;

    int*   wsI = (int*)ws;       // barrier slots: 17 x 256 B lines
    float* XR  = ws + 2048;      // 8 KiB offset; 33.5 MB region in d_ws

    // Preload ALL levels' child indices (one coalesced load each): idx-load
    // latency never touches the per-level critical path.
    const int pbase = blockIdx.x * NPB + w * NPW;
    int vidx[NLEV - 1];
    #pragma unroll
    for (int L = 1; L < NLEV; ++L)
        vidx[L - 1] = src[(long)(L - 1) * EPL + pbase * CPN + lane];

    phaseA<true>(x, Wr, out, XR, lane, w, blockIdx.x, sbuf[w]);
    gridbar_tree(wsI, 0);

    float wl[DIM];
    load_wrow(wl, Wl, lane);
    const float bias = bl[lane];

    #pragma unroll
    for (int L = 1; L < NLEV; ++L) {
        phaseB<true>(vidx[L - 1], XR, out, wl, bias, L, lane, w,
                     blockIdx.x, sbuf[w]);
        if (L + 1 < NLEV)
            gridbar_tree(wsI, L);
    }
}

// ---------------- Fallback: normal launches (kernel-boundary coherence) ----
__global__ __launch_bounds__(TPB) void dag_phaseA_k(
    const float* __restrict__ x, const float* __restrict__ Wr,
    float* __restrict__ out, float* __restrict__ ws)
{
    __shared__ __align__(16) float sbuf[WPB][256];
    const int lane = threadIdx.x & 63;
    const int w    = threadIdx.x >> 6;
    phaseA<false>(x, Wr, out, ws + 2048, lane, w, blockIdx.x, sbuf[w]);
}

__global__ __launch_bounds__(TPB) void dag_phaseB_k(
    const int* __restrict__ src, const float* __restrict__ Wl,
    const float* __restrict__ bl, float* __restrict__ out,
    float* __restrict__ ws, int L)
{
    __shared__ __align__(16) float sbuf[WPB][256];
    const int lane = threadIdx.x & 63;
    const int w    = threadIdx.x >> 6;
    const int pbase = blockIdx.x * NPB + w * NPW;
    int vidx = src[(long)(L - 1) * EPL + pbase * CPN + lane];
    float wl[DIM];
    load_wrow(wl, Wl, lane);
    phaseB<false>(vidx, ws + 2048, out, wl, bl[lane], L, lane, w,
                  blockIdx.x, sbuf[w]);
}

extern "C" void kernel_launch(void* const* d_in, const int* in_sizes, int n_in,
                              void* d_out, int out_size, void* d_ws, size_t ws_size,
                              hipStream_t stream) {
    const float* x  = (const float*)d_in[0];   // [131072,64] f32
    const int*   ei = (const int*)d_in[1];     // [2, 917504] int32
    const float* Wl = (const float*)d_in[2];   // [64,64] f32
    const float* bl = (const float*)d_in[3];   // [64]    f32
    const float* Wr = (const float*)d_in[4];   // [64,64] f32
    float* out = (float*)d_out;                // [131072,64] f32
    float* ws  = (float*)d_ws;                 // [0..2047]=barrier slots, rest XR

    const int* src = ei;                       // first E entries = src row

    // Zero all barrier slots inside the captured work (d_ws is re-poisoned
    // 0xAA before every timed launch). XR needs no init (fully overwritten).
    hipMemsetAsync(ws, 0, 8192, stream);

    void* args[] = {(void*)&x, (void*)&src, (void*)&Wl, (void*)&bl,
                    (void*)&Wr, (void*)&out, (void*)&ws};
    hipError_t e = hipLaunchCooperativeKernel((const void*)dag_fused,
                                              dim3(CBLOCKS), dim3(TPB),
                                              args, 0, stream);
    if (e != hipSuccess) {
        (void)hipGetLastError();               // clear sticky error
        hipLaunchKernelGGL(dag_phaseA_k, dim3(CBLOCKS), dim3(TPB), 0, stream,
                           x, Wr, out, ws);
        for (int L = 1; L < NLEV; ++L) {
            hipLaunchKernelGGL(dag_phaseB_k, dim3(CBLOCKS), dim3(TPB), 0, stream,
                               src, Wl, bl, out, ws, L);
        }
    }
}

// Round 10
// 195.981 us; speedup vs baseline: 1.9531x; 1.0181x over previous
//
#include <hip/hip_runtime.h>

// Problem constants (fixed instance): all float tensors are float32 on device.
#define NPL   16384        // nodes per level
#define DIM   64
#define CPN   8            // children per node
#define EPL   (NPL * CPN)  // edges per level block = 131072
#define NLEV  8

#define TPB     512        // 8 waves/block -> 92 VGPRs, no spill (R0 proven).
                           // TPB=1024 pins a 64-VGPR cap -> spills (R3-R5).
#define WPB     (TPB / 64)
#define CBLOCKS 256        // 1 block/CU. 2 blocks/CU was 2.25x worse (R7).
#define NPB     (NPL / CBLOCKS)   // 64 nodes per block per level
#define NPW     (NPB / WPB)       // 8 nodes per wave per level

#define SPIN_CAP (1 << 24) // ~16M spin iters (~0.5-1 s) >> us-scale barriers.
                           // R9 lesson: a hang gives "container failed" (no
                           // data); a capped spin gives passed:false (data).

// ---- barrier layout in ws (int units) -------------------------------------
//   arr[b]  = wsI + b*16      (b=0..255, 64-B spacing: own line per block)
//   rel[g]  = wsI + 4096+g*64 (g=0..7, 256-B spacing)
//   XR region starts at ws + 8192 floats (32 KiB); memset 32 KiB at launch.
// Arrival = +1 to OWN line (no contention, no serialization; R8's tree had
// 32 serialized adds/line ~= 3-5us/barrier). Detection = block 0 wave 0
// sweeps 256 flags (4 loads/lane + ballot). Release = 8 flag lines,
// <=31 pollers each. Monotonic rounds: no resets, no ABA.

__device__ __forceinline__ void co_st(float* p, float v) {
    __hip_atomic_store(p, v, __ATOMIC_RELAXED, __HIP_MEMORY_SCOPE_AGENT);
}

__device__ __forceinline__ void load_wrow(float* dst, const float* W, int row) {
    const float4* p = (const float4*)(W + row * DIM);
    #pragma unroll
    for (int q = 0; q < DIM / 4; ++q) {
        float4 v = p[q];
        dst[4*q+0] = v.x; dst[4*q+1] = v.y;
        dst[4*q+2] = v.z; dst[4*q+3] = v.w;
    }
}

// tanh via hardware exp + rcp. |err| ~1e-6, threshold is 5.9e-2.
__device__ __forceinline__ float fast_tanh(float z) {
    z = fminf(15.f, fmaxf(-15.f, z));
    float e = __expf(-2.f * z);
    return (1.f - e) * __builtin_amdgcn_rcpf(1.f + e);
}

// Arrive: __syncthreads drains vmcnt (all data stores acked at the coherent
// point), then one uncontended add to this block's own flag line.
__device__ __forceinline__ void bar_arrive(int* wsI) {
    __syncthreads();
    if (threadIdx.x == 0)
        __hip_atomic_fetch_add(wsI + blockIdx.x * 16, 1, __ATOMIC_RELAXED,
                               __HIP_MEMORY_SCOPE_AGENT);
}

// Wait: block 0 wave 0 detects (wave-parallel sweep, no atomics), then
// releases via 8 flag lines; other blocks poll their group's line.
// All spins are CAPPED: on cap-expiry we proceed (wrong answer, not hang).
__device__ __forceinline__ void bar_wait(int* wsI, int round) {
    const int tgt = round + 1;
    if (blockIdx.x == 0) {
        if (threadIdx.x < 64) {
            const int l = threadIdx.x;
            int* a0 = wsI + l * 16;
            int* a1 = wsI + (l + 64) * 16;
            int* a2 = wsI + (l + 128) * 16;
            int* a3 = wsI + (l + 192) * 16;
            for (int it = 0; it < SPIN_CAP; ++it) {
                int m0 = __hip_atomic_load(a0, __ATOMIC_RELAXED,
                                           __HIP_MEMORY_SCOPE_AGENT);
                int m1 = __hip_atomic_load(a1, __ATOMIC_RELAXED,
                                           __HIP_MEMORY_SCOPE_AGENT);
                int m2 = __hip_atomic_load(a2, __ATOMIC_RELAXED,
                                           __HIP_MEMORY_SCOPE_AGENT);
                int m3 = __hip_atomic_load(a3, __ATOMIC_RELAXED,
                                           __HIP_MEMORY_SCOPE_AGENT);
                bool ok = (m0 >= tgt) & (m1 >= tgt) & (m2 >= tgt) & (m3 >= tgt);
                if (__ballot(ok) == ~0ull) break;
                __builtin_amdgcn_s_sleep(1);
            }
            if (l < 8)
                __hip_atomic_store(wsI + 4096 + l * 64, tgt, __ATOMIC_RELAXED,
                                   __HIP_MEMORY_SCOPE_AGENT);
        }
    } else if (threadIdx.x == 0) {
        int* rel = wsI + 4096 + (blockIdx.x >> 5) * 64;
        for (int it = 0; it < SPIN_CAP; ++it) {
            if (__hip_atomic_load(rel, __ATOMIC_RELAXED,
                                  __HIP_MEMORY_SCOPE_AGENT) >= tgt) break;
            __builtin_amdgcn_s_sleep(1);
        }
    }
    asm volatile("" ::: "memory");
    __syncthreads();
}

// ------------- Phase A: x @ Wr^T for ALL 131072 rows -----------------------
// Level-0 rows (groups 0..GPL-1) go straight to out -> write-through; they
// are the ONLY phase-A data other blocks gather. With SB (split-barrier), we
// ARRIVE at bar0 right after the L0 groups, then compute levels 1-7's XR
// (self-consumed, cached path) WHILE the barrier propagates; caller waits.
// (R1/R2: XR belongs in GLOBAL; VGPR home spilled, LDS home perturbed
// regalloc. Traffic is not the bottleneck.)
template<bool COH, bool SB>
__device__ __forceinline__ void phaseA(
    const float* __restrict__ x, const float* __restrict__ Wr,
    float* __restrict__ out, float* __restrict__ XR,
    int lane, int w, int blk, float* sX4, int* wsI)
{
    constexpr int GPL = NPW / 4;           // 4-row groups per level (2)
    constexpr int NG  = NLEV * GPL;        // 16 groups total per wave

    float wr[DIM];
    load_wrow(wr, Wr, lane);

    const int base = blk * NPB + w * NPW;
    const int sub  = lane >> 4;            // row within 4-row group
    const int col4 = (lane & 15) * 4;      // dim offset of this lane's float4

    float4 q0, q1, q2;
    #define ROWB(g) ((long)((g) / GPL) * NPL + base + ((g) % GPL) * 4)
    q0 = *(const float4*)&x[(ROWB(0) + sub) * DIM + col4];
    q1 = *(const float4*)&x[(ROWB(1) + sub) * DIM + col4];

    #pragma unroll
    for (int g = 0; g < NG; ++g) {
        if (g + 2 < NG)
            q2 = *(const float4*)&x[(ROWB(g + 2) + sub) * DIM + col4];

        *(float4*)&sX4[sub * DIM + col4] = q0;  // stage 4 rows (in-order DS)

        const long rb = ROWB(g);
        const int  L  = g / GPL;
        #pragma unroll
        for (int rr = 0; rr < 4; ++rr) {
            float a0 = 0.f, a1 = 0.f, a2 = 0.f, a3 = 0.f;
            const float4* A = (const float4*)&sX4[rr * DIM];   // broadcast
            #pragma unroll
            for (int k = 0; k < DIM / 4; ++k) {
                float4 av = A[k];
                a0 += av.x * wr[4*k+0];
                a1 += av.y * wr[4*k+1];
                a2 += av.z * wr[4*k+2];
                a3 += av.w * wr[4*k+3];
            }
            float r = (a0 + a1) + (a2 + a3);
            const long gg = rb + rr;
            if (L == 0) {
                float* d = &out[gg * DIM + lane];
                if (COH) co_st(d, r); else *d = r;
            } else {
                XR[gg * DIM + lane] = r;          // same-wave consumer: cached
            }
        }
        q0 = q1; q1 = q2;

        if (SB && g == GPL - 1)
            bar_arrive(wsI);     // L0 stores drained -> arrive; XR overlaps
    }
    #undef ROWB
}

// -------- Phase B: out[g] = tanh(XR[g] + agg·Wl^T + b) for one level -------
// vidx: lane l holds child index of node (pbase + l/8), slot (l%8), preloaded
// at kernel start. Gathers are NORMAL CACHED loads. Stores are write-through.
// 4-SLOT ring, prefetch distance 3: issue slot (c+3)&3 never collides with
// consume slot c&3.
template<bool COH>
__device__ __forceinline__ void phaseB(
    int vidx, const float* __restrict__ XR, float* __restrict__ out,
    const float* wl, float bias, int L, int lane, int w, int blk, float* sA)
{
    const int  pbase = blk * NPB + w * NPW;
    const long gbase = (long)L * NPL;

    float g[4][CPN];
    float xr[4];

    #define ISSUE(c, s)                                                       \
        {                                                                     \
            _Pragma("unroll")                                                 \
            for (int j = 0; j < CPN; ++j) {                                   \
                int si = __builtin_amdgcn_readlane(vidx, (c) * CPN + j);      \
                g[s][j] = out[(long)si * DIM + lane];   /* cached gather */   \
            }                                                                 \
            xr[s] = XR[(gbase + pbase + (c)) * DIM + lane];                   \
        }

    ISSUE(0, 0);
    ISSUE(1, 1);
    ISSUE(2, 2);

    #pragma unroll
    for (int c = 0; c < NPW; ++c) {
        const int slot = c & 3;
        if (c + 3 < NPW) ISSUE(c + 3, (c + 3) & 3);   // != slot, always

        // Tree-sum the 8 children (3-deep instead of 8-deep chain).
        float s0 = g[slot][0] + g[slot][1];
        float s1 = g[slot][2] + g[slot][3];
        float s2 = g[slot][4] + g[slot][5];
        float s3 = g[slot][6] + g[slot][7];
        float agg = (s0 + s1) + (s2 + s3);
        sA[lane] = agg;                            // per-wave slot, in-order DS

        float a0 = 0.f, a1 = 0.f, a2 = 0.f, a3 = bias + xr[slot];
        const float4* B = (const float4*)sA;       // broadcast: conflict-free
        #pragma unroll
        for (int k = 0; k < DIM / 4; ++k) {
            float4 bv = B[k];
            a0 += bv.x * wl[4*k+0];
            a1 += bv.y * wl[4*k+1];
            a2 += bv.z * wl[4*k+2];
            a3 += bv.w * wl[4*k+3];
        }
        float r = fast_tanh((a0 + a1) + (a2 + a3));
        float* d = &out[(gbase + pbase + c) * DIM + lane];
        if (COH) co_st(d, r); else *d = r;
    }
    #undef ISSUE
}

// ---------------- Fused cooperative kernel (1 dispatch) ----------------
__global__ __launch_bounds__(TPB, 2) void dag_fused(
    const float* __restrict__ x, const int* __restrict__ src,
    const float* __restrict__ Wl, const float* __restrict__ bl,
    const float* __restrict__ Wr, float* __restrict__ out,
    float* __restrict__ ws)
{
    __shared__ __align__(16) float sbuf[WPB][256];

    const int lane = threadIdx.x & 63;
    const int w    = threadIdx.x >> 6;

    int*   wsI = (int*)ws;       // barrier flags: arr 16 KiB + rel 2 KiB
    float* XR  = ws + 8192;      // 32 KiB offset; 33.5 MB region in d_ws

    // Preload ALL levels' child indices (one coalesced load each): idx-load
    // latency never touches the per-level critical path.
    const int pbase = blockIdx.x * NPB + w * NPW;
    int vidx[NLEV - 1];
    #pragma unroll
    for (int L = 1; L < NLEV; ++L)
        vidx[L - 1] = src[(long)(L - 1) * EPL + pbase * CPN + lane];

    // Phase A: L0 -> arrive(bar0) -> XR(levels 1-7) overlapped -> wait.
    phaseA<true, true>(x, Wr, out, XR, lane, w, blockIdx.x, sbuf[w], wsI);
    bar_wait(wsI, 0);

    float wl[DIM];
    load_wrow(wl, Wl, lane);
    const float bias = bl[lane];

    #pragma unroll
    for (int L = 1; L < NLEV; ++L) {
        phaseB<true>(vidx[L - 1], XR, out, wl, bias, L, lane, w,
                     blockIdx.x, sbuf[w]);
        if (L + 1 < NLEV) {
            bar_arrive(wsI);
            bar_wait(wsI, L);
        }
    }
}

// ---------------- Fallback: normal launches (kernel-boundary coherence) ----
__global__ __launch_bounds__(TPB) void dag_phaseA_k(
    const float* __restrict__ x, const float* __restrict__ Wr,
    float* __restrict__ out, float* __restrict__ ws)
{
    __shared__ __align__(16) float sbuf[WPB][256];
    const int lane = threadIdx.x & 63;
    const int w    = threadIdx.x >> 6;
    phaseA<false, false>(x, Wr, out, ws + 8192, lane, w, blockIdx.x,
                         sbuf[w], nullptr);
}

__global__ __launch_bounds__(TPB) void dag_phaseB_k(
    const int* __restrict__ src, const float* __restrict__ Wl,
    const float* __restrict__ bl, float* __restrict__ out,
    float* __restrict__ ws, int L)
{
    __shared__ __align__(16) float sbuf[WPB][256];
    const int lane = threadIdx.x & 63;
    const int w    = threadIdx.x >> 6;
    const int pbase = blockIdx.x * NPB + w * NPW;
    int vidx = src[(long)(L - 1) * EPL + pbase * CPN + lane];
    float wl[DIM];
    load_wrow(wl, Wl, lane);
    phaseB<false>(vidx, ws + 8192, out, wl, bl[lane], L, lane, w,
                  blockIdx.x, sbuf[w]);
}

extern "C" void kernel_launch(void* const* d_in, const int* in_sizes, int n_in,
                              void* d_out, int out_size, void* d_ws, size_t ws_size,
                              hipStream_t stream) {
    const float* x  = (const float*)d_in[0];   // [131072,64] f32
    const int*   ei = (const int*)d_in[1];     // [2, 917504] int32
    const float* Wl = (const float*)d_in[2];   // [64,64] f32
    const float* bl = (const float*)d_in[3];   // [64]    f32
    const float* Wr = (const float*)d_in[4];   // [64,64] f32
    float* out = (float*)d_out;                // [131072,64] f32
    float* ws  = (float*)d_ws;                 // [0..32KiB)=barrier flags, rest XR

    const int* src = ei;                       // first E entries = src row

    // Zero all barrier flag lines inside the captured work (d_ws is
    // re-poisoned 0xAA before every timed launch). XR needs no init.
    hipMemsetAsync(ws, 0, 32768, stream);

    void* args[] = {(void*)&x, (void*)&src, (void*)&Wl, (void*)&bl,
                    (void*)&Wr, (void*)&out, (void*)&ws};
    hipError_t e = hipLaunchCooperativeKernel((const void*)dag_fused,
                                              dim3(CBLOCKS), dim3(TPB),
                                              args, 0, stream);
    if (e != hipSuccess) {
        (void)hipGetLastError();               // clear sticky error
        hipLaunchKernelGGL(dag_phaseA_k, dim3(CBLOCKS), dim3(TPB), 0, stream,
                           x, Wr, out, ws);
        for (int L = 1; L < NLEV; ++L) {
            hipLaunchKernelGGL(dag_phaseB_k, dim3(CBLOCKS), dim3(TPB), 0, stream,
                               src, Wl, bl, out, ws, L);
        }
    }
}